// Round 6
// baseline (129.707 us; speedup 1.0000x reference)
//
#include <hip/hip_runtime.h>
#include <hip/hip_bf16.h>
#include <math.h>

// PINN forward + Taylor-mode derivatives (orders 0..4), closed form.
// 2 points/thread in <2 x float> (VOP3P packed fp32).
// Round 6 = round 5 resubmitted (GPU broker timeout, never ran).
// __builtin_nontemporal_* need clang-native ext_vector_type pointers, not
// HIP_vector_type float4/float2 classes.
// __launch_bounds__(256,1) -> 256-VGPR budget (round 3's (256,2) capped at
// 128 VGPR vs ~120-reg natural live set -> allocator thrash).
// Outputs per point: [u, u_x, u_xx, w, w_x, w_xx, w_xxx, w_xxxx] (row-major [N,8])

typedef float v2f __attribute__((ext_vector_type(2)));
typedef float v4f __attribute__((ext_vector_type(4)));

__device__ __forceinline__ v2f bc(float s) { v2f r; r.x = s; r.y = s; return r; }
__device__ __forceinline__ v2f vfma(v2f a, v2f b, v2f c) {
    return __builtin_elementwise_fma(a, b, c);
}
__device__ __forceinline__ v4f mk4(float a, float b, float c, float d) {
    v4f r; r.x = a; r.y = b; r.z = c; r.w = d; return r;
}

__device__ __forceinline__ float fast_rcp(float x) { return __builtin_amdgcn_rcpf(x); }
__device__ __forceinline__ float fast_exp2(float x) { return __builtin_amdgcn_exp2f(x); }

// tanh(z) = 1 - 2/(exp(2z)+1); exp2->inf: rcp(inf)=0 -> 1; exp2->0: rcp(1)=1 -> -1.
__device__ __forceinline__ v2f tanh2(v2f z) {
    const v2f a = bc(2.88539008177792681472f) * z;   // 2*log2(e)*z, packed
    v2f e;
    e.x = fast_exp2(a.x);
    e.y = fast_exp2(a.y);
    const v2f ep1 = e + bc(1.f);
    v2f r;
    r.x = fast_rcp(ep1.x);
    r.y = fast_rcp(ep1.y);
    return vfma(bc(-2.f), r, bc(1.f));
}

__global__ __launch_bounds__(256, 1) void pinn_taylor_kernel(
    const float* __restrict__ x,
    const float* __restrict__ W0, const float* __restrict__ b0,
    const float* __restrict__ W1, const float* __restrict__ b1,
    const float* __restrict__ W2, const float* __restrict__ b2,
    float* __restrict__ out, int n)
{
    const int i  = blockIdx.x * blockDim.x + threadIdx.x;
    const int p0 = 2 * i;
    if (p0 >= n) return;
    const bool full = (p0 + 1 < n);

    v2f xv;
    if (full) {
        xv = __builtin_nontemporal_load(reinterpret_cast<const v2f*>(x + p0));
    } else {
        xv.x = x[p0]; xv.y = 0.f;
    }

    // Layer-1 pre-activation Taylor accumulators, orders 0..4, 8 neurons, 2 pts
    v2f g0[8], g1[8], g2[8], g3[8], g4[8];

    // ---- layer 0 (affine in x) fused into layer-1 matvec over all 5 orders
    #pragma unroll
    for (int j = 0; j < 8; ++j) {
        const float a  = W0[j];                  // W0 shape (8,1)
        const v2f   z  = vfma(bc(a), xv, bc(b0[j]));
        const v2f   t  = tanh2(z);
        const v2f   s  = vfma(-t, t, bc(1.f));   // sech^2
        const v2f   ts = t * s;
        const v2f   t2 = t * t;
        const v2f   s2 = s * s;
        const v2f   T2 = bc(-2.f) * ts;
        const v2f   T3 = vfma(bc(4.f) * t2, s, bc(-2.f) * s2);
        const v2f   T4 = ts * vfma(bc(-8.f), t2, bc(16.f) * s);
        const float a2 = a * a;
        const float a3 = a2 * a;
        const float a4 = a2 * a2;
        const v2f d0 = t;
        const v2f d1 = bc(a)  * s;
        const v2f d2 = bc(a2) * T2;
        const v2f d3 = bc(a3) * T3;
        const v2f d4 = bc(a4) * T4;
        #pragma unroll
        for (int ii = 0; ii < 8; ++ii) {
            const float w = W1[ii * 8 + j];      // W1 shape (8,8) row-major
            if (j == 0) {                        // peel: kills zero/bias init movs
                g0[ii] = vfma(bc(w), d0, bc(b1[ii]));
                g1[ii] = bc(w) * d1;
                g2[ii] = bc(w) * d2;
                g3[ii] = bc(w) * d3;
                g4[ii] = bc(w) * d4;
            } else {
                g0[ii] = vfma(bc(w), d0, g0[ii]);
                g1[ii] = vfma(bc(w), d1, g1[ii]);
                g2[ii] = vfma(bc(w), d2, g2[ii]);
                g3[ii] = vfma(bc(w), d3, g3[ii]);
                g4[ii] = vfma(bc(w), d4, g4[ii]);
            }
        }
    }

    // Output heads: u needs orders 0..2 only, w needs 0..4
    v2f ou0 = bc(b2[0]), ou1 = bc(0.f), ou2 = bc(0.f);
    v2f ow0 = bc(b2[1]), ow1 = bc(0.f), ow2 = bc(0.f), ow3 = bc(0.f), ow4 = bc(0.f);

    // ---- layer 1 tanh via Faa di Bruno, fused into layer-2 linear
    #pragma unroll
    for (int ii = 0; ii < 8; ++ii) {
        const v2f G1 = g1[ii], G2 = g2[ii], G3 = g3[ii], G4 = g4[ii];
        const v2f t  = tanh2(g0[ii]);
        const v2f s  = vfma(-t, t, bc(1.f));
        const v2f ts = t * s;
        const v2f t2 = t * t;
        const v2f s2 = s * s;
        const v2f T2 = bc(-2.f) * ts;
        const v2f T3 = vfma(bc(4.f) * t2, s, bc(-2.f) * s2);
        const v2f T4 = ts * vfma(bc(-8.f), t2, bc(16.f) * s);

        const v2f G1_2 = G1 * G1;
        const v2f d0 = t;
        const v2f d1 = s * G1;
        const v2f d2 = vfma(T2, G1_2, s * G2);
        const v2f d3 = vfma(T3, G1_2 * G1, vfma(bc(3.f) * T2, G1 * G2, s * G3));
        const v2f d4 = vfma(T4, G1_2 * G1_2,
                        vfma(bc(6.f) * T3, G1_2 * G2,
                         vfma(T2, vfma(bc(3.f), G2 * G2, bc(4.f) * (G1 * G3)), s * G4)));

        const float wu = W2[ii];       // W2 (2,8) row-major: row 0 = u
        const float ww = W2[8 + ii];   //                     row 1 = w
        ou0 = vfma(bc(wu), d0, ou0); ou1 = vfma(bc(wu), d1, ou1); ou2 = vfma(bc(wu), d2, ou2);
        ow0 = vfma(bc(ww), d0, ow0); ow1 = vfma(bc(ww), d1, ow1); ow2 = vfma(bc(ww), d2, ow2);
        ow3 = vfma(bc(ww), d3, ow3); ow4 = vfma(bc(ww), d4, ow4);
    }

    // output rows: u, u_x, u_xx, w, w_x, w_xx, w_xxx, w_xxxx  (streaming -> NT stores)
    v4f* out4 = reinterpret_cast<v4f*>(out);
    __builtin_nontemporal_store(mk4(ou0.x, ou1.x, ou2.x, ow0.x), out4 + 4 * i + 0);
    __builtin_nontemporal_store(mk4(ow1.x, ow2.x, ow3.x, ow4.x), out4 + 4 * i + 1);
    if (full) {
        __builtin_nontemporal_store(mk4(ou0.y, ou1.y, ou2.y, ow0.y), out4 + 4 * i + 2);
        __builtin_nontemporal_store(mk4(ow1.y, ow2.y, ow3.y, ow4.y), out4 + 4 * i + 3);
    }
}

extern "C" void kernel_launch(void* const* d_in, const int* in_sizes, int n_in,
                              void* d_out, int out_size, void* d_ws, size_t ws_size,
                              hipStream_t stream) {
    const float* x  = (const float*)d_in[0];
    const float* W0 = (const float*)d_in[1];
    const float* b0 = (const float*)d_in[2];
    const float* W1 = (const float*)d_in[3];
    const float* b1 = (const float*)d_in[4];
    const float* W2 = (const float*)d_in[5];
    const float* b2 = (const float*)d_in[6];
    float* out = (float*)d_out;

    const int n = in_sizes[0];
    const int nthreads = (n + 1) / 2;
    const int block = 256;
    const int grid = (nthreads + block - 1) / block;
    pinn_taylor_kernel<<<grid, block, 0, stream>>>(x, W0, b0, W1, b1, W2, b2, out, n);
}

// Round 7
// 110.373 us; speedup vs baseline: 1.1752x; 1.1752x over previous
//
#include <hip/hip_runtime.h>
#include <hip/hip_bf16.h>
#include <math.h>

// PINN forward + Taylor-mode derivatives (orders 0..4), closed form.
// 2 points/thread (amortization only — packed fp32 is half-rate on CDNA4, so
// v2f is just notation; scalarized codegen is within 11% of ideal op count,
// measured round 6: 1824 issues/wave vs 1640 ideal).
// Round 7: revert round-6 regressions (NT stores caused 1.7x write
// amplification, WRITE_SIZE 62.5->105 MB, VALUBusy 80->40%); plain cached
// stores + __launch_bounds__(256,2). T3/T4 refactored to drop s^2 (~32 ops/pt).
// Outputs per point: [u, u_x, u_xx, w, w_x, w_xx, w_xxx, w_xxxx] (row-major [N,8])

typedef float v2f __attribute__((ext_vector_type(2)));
typedef float v4f __attribute__((ext_vector_type(4)));

__device__ __forceinline__ v2f bc(float s) { v2f r; r.x = s; r.y = s; return r; }
__device__ __forceinline__ v2f vfma(v2f a, v2f b, v2f c) {
    return __builtin_elementwise_fma(a, b, c);
}
__device__ __forceinline__ v4f mk4(float a, float b, float c, float d) {
    v4f r; r.x = a; r.y = b; r.z = c; r.w = d; return r;
}

__device__ __forceinline__ float fast_rcp(float x) { return __builtin_amdgcn_rcpf(x); }
__device__ __forceinline__ float fast_exp2(float x) { return __builtin_amdgcn_exp2f(x); }

// tanh(z) = 1 - 2/(exp(2z)+1); exp2->inf: rcp(inf)=0 -> 1; exp2->0: rcp(1)=1 -> -1.
__device__ __forceinline__ v2f tanh2(v2f z) {
    const v2f a = bc(2.88539008177792681472f) * z;   // 2*log2(e)*z
    v2f e;
    e.x = fast_exp2(a.x);
    e.y = fast_exp2(a.y);
    const v2f ep1 = e + bc(1.f);
    v2f r;
    r.x = fast_rcp(ep1.x);
    r.y = fast_rcp(ep1.y);
    return vfma(bc(-2.f), r, bc(1.f));
}

__global__ __launch_bounds__(256, 2) void pinn_taylor_kernel(
    const float* __restrict__ x,
    const float* __restrict__ W0, const float* __restrict__ b0,
    const float* __restrict__ W1, const float* __restrict__ b1,
    const float* __restrict__ W2, const float* __restrict__ b2,
    float* __restrict__ out, int n)
{
    const int i  = blockIdx.x * blockDim.x + threadIdx.x;
    const int p0 = 2 * i;
    if (p0 >= n) return;
    const bool full = (p0 + 1 < n);

    v2f xv;
    if (full) {
        xv = *reinterpret_cast<const v2f*>(x + p0);
    } else {
        xv.x = x[p0]; xv.y = 0.f;
    }

    // Layer-1 pre-activation Taylor accumulators, orders 0..4, 8 neurons, 2 pts
    v2f g0[8], g1[8], g2[8], g3[8], g4[8];

    // ---- layer 0 (affine in x) fused into layer-1 matvec over all 5 orders
    #pragma unroll
    for (int j = 0; j < 8; ++j) {
        const float a  = W0[j];                  // W0 shape (8,1)
        const v2f   z  = vfma(bc(a), xv, bc(b0[j]));
        const v2f   t  = tanh2(z);
        const v2f   s  = vfma(-t, t, bc(1.f));   // sech^2 = 1 - t^2
        const v2f   ts = t * s;
        const v2f   t2 = t * t;
        const v2f   T2 = bc(-2.f) * ts;
        const v2f   T3 = s * vfma(bc(6.f), t2, bc(-2.f));          // s(6t^2-2)
        const v2f   T4 = (bc(8.f) * ts) * vfma(bc(2.f), s, -t2);   // 8ts(2s-t^2)
        const float a2 = a * a;
        const float a3 = a2 * a;
        const float a4 = a2 * a2;
        const v2f d0 = t;
        const v2f d1 = bc(a)  * s;
        const v2f d2 = bc(a2) * T2;
        const v2f d3 = bc(a3) * T3;
        const v2f d4 = bc(a4) * T4;
        #pragma unroll
        for (int ii = 0; ii < 8; ++ii) {
            const float w = W1[ii * 8 + j];      // W1 shape (8,8) row-major
            if (j == 0) {                        // peel: kills zero/bias init movs
                g0[ii] = vfma(bc(w), d0, bc(b1[ii]));
                g1[ii] = bc(w) * d1;
                g2[ii] = bc(w) * d2;
                g3[ii] = bc(w) * d3;
                g4[ii] = bc(w) * d4;
            } else {
                g0[ii] = vfma(bc(w), d0, g0[ii]);
                g1[ii] = vfma(bc(w), d1, g1[ii]);
                g2[ii] = vfma(bc(w), d2, g2[ii]);
                g3[ii] = vfma(bc(w), d3, g3[ii]);
                g4[ii] = vfma(bc(w), d4, g4[ii]);
            }
        }
    }

    // Output heads: u needs orders 0..2 only, w needs 0..4
    v2f ou0 = bc(b2[0]), ou1 = bc(0.f), ou2 = bc(0.f);
    v2f ow0 = bc(b2[1]), ow1 = bc(0.f), ow2 = bc(0.f), ow3 = bc(0.f), ow4 = bc(0.f);

    // ---- layer 1 tanh via Faa di Bruno, fused into layer-2 linear
    #pragma unroll
    for (int ii = 0; ii < 8; ++ii) {
        const v2f G1 = g1[ii], G2 = g2[ii], G3 = g3[ii], G4 = g4[ii];
        const v2f t  = tanh2(g0[ii]);
        const v2f s  = vfma(-t, t, bc(1.f));
        const v2f ts = t * s;
        const v2f t2 = t * t;
        const v2f T2 = bc(-2.f) * ts;
        const v2f T3 = s * vfma(bc(6.f), t2, bc(-2.f));
        const v2f T4 = (bc(8.f) * ts) * vfma(bc(2.f), s, -t2);

        const v2f G1_2 = G1 * G1;
        const v2f d0 = t;
        const v2f d1 = s * G1;
        const v2f d2 = vfma(T2, G1_2, s * G2);
        const v2f d3 = vfma(T3, G1_2 * G1, vfma(bc(3.f) * T2, G1 * G2, s * G3));
        const v2f d4 = vfma(T4, G1_2 * G1_2,
                        vfma(bc(6.f) * T3, G1_2 * G2,
                         vfma(T2, vfma(bc(3.f), G2 * G2, bc(4.f) * (G1 * G3)), s * G4)));

        const float wu = W2[ii];       // W2 (2,8) row-major: row 0 = u
        const float ww = W2[8 + ii];   //                     row 1 = w
        ou0 = vfma(bc(wu), d0, ou0); ou1 = vfma(bc(wu), d1, ou1); ou2 = vfma(bc(wu), d2, ou2);
        ow0 = vfma(bc(ww), d0, ow0); ow1 = vfma(bc(ww), d1, ow1); ow2 = vfma(bc(ww), d2, ow2);
        ow3 = vfma(bc(ww), d3, ow3); ow4 = vfma(bc(ww), d4, ow4);
    }

    // output rows: u, u_x, u_xx, w, w_x, w_xx, w_xxx, w_xxxx  (plain cached stores)
    v4f* out4 = reinterpret_cast<v4f*>(out);
    out4[4 * i + 0] = mk4(ou0.x, ou1.x, ou2.x, ow0.x);
    out4[4 * i + 1] = mk4(ow1.x, ow2.x, ow3.x, ow4.x);
    if (full) {
        out4[4 * i + 2] = mk4(ou0.y, ou1.y, ou2.y, ow0.y);
        out4[4 * i + 3] = mk4(ow1.y, ow2.y, ow3.y, ow4.y);
    }
}

extern "C" void kernel_launch(void* const* d_in, const int* in_sizes, int n_in,
                              void* d_out, int out_size, void* d_ws, size_t ws_size,
                              hipStream_t stream) {
    const float* x  = (const float*)d_in[0];
    const float* W0 = (const float*)d_in[1];
    const float* b0 = (const float*)d_in[2];
    const float* W1 = (const float*)d_in[3];
    const float* b1 = (const float*)d_in[4];
    const float* W2 = (const float*)d_in[5];
    const float* b2 = (const float*)d_in[6];
    float* out = (float*)d_out;

    const int n = in_sizes[0];
    const int nthreads = (n + 1) / 2;
    const int block = 256;
    const int grid = (nthreads + block - 1) / block;
    pinn_taylor_kernel<<<grid, block, 0, stream>>>(x, W0, b0, W1, b1, W2, b2, out, n);
}